// Round 3
// baseline (319.743 us; speedup 1.0000x reference)
//
#include <hip/hip_runtime.h>
#include <stdint.h>

typedef __attribute__((ext_vector_type(4))) float f32x4;
typedef __attribute__((ext_vector_type(8))) __bf16 bf16x8;

__device__ __forceinline__ unsigned short f2bf(float f) {
  union { float f; unsigned u; } v; v.f = f;
  unsigned r = v.u + 0x7FFF + ((v.u >> 16) & 1);
  return (unsigned short)(r >> 16);
}

__device__ __forceinline__ void g2l16(const void* g, void* l) {
  __builtin_amdgcn_global_load_lds((const __attribute__((address_space(1))) void*)g,
                                   (__attribute__((address_space(3))) void*)l, 16, 0, 0);
}

// ---------------- weight fp32 -> bf16 ----------------
__global__ void cvt_weights(const float* __restrict__ a, const float* __restrict__ p,
                            unsigned short* __restrict__ wa, unsigned short* __restrict__ wp) {
  int i = blockIdx.x * 256 + threadIdx.x;
  if (i < 786432) wa[i] = f2bf(a[i]);
  else wp[i - 786432] = f2bf(p[i - 786432]);
}

// ---------------- fused groupnorm: stats + normalize + transpose ----------------
// one block per (b,g): 64 ch x 1024 px. second read is L2/L3-warm.
__global__ __launch_bounds__(256) void gn_fused(
    const float* __restrict__ x, const float* __restrict__ gw, const float* __restrict__ gb,
    unsigned short* __restrict__ xnT) {
  __shared__ float tile[64][65];
  __shared__ float red[8];
  __shared__ float mv[2];
  int bid = blockIdx.x;             // b*8+g
  int g = bid & 7, b = bid >> 3;
  int t = threadIdx.x;
  const float4* p = (const float4*)(x + (size_t)bid * 65536);
  float s = 0.f, ss = 0.f;
  for (int i = t; i < 16384; i += 256) {
    float4 v = p[i];
    s += v.x + v.y + v.z + v.w;
    ss += v.x * v.x + v.y * v.y + v.z * v.z + v.w * v.w;
  }
#pragma unroll
  for (int o = 32; o > 0; o >>= 1) {
    s += __shfl_down(s, o, 64);
    ss += __shfl_down(ss, o, 64);
  }
  int w = t >> 6;
  if ((t & 63) == 0) { red[w] = s; red[4 + w] = ss; }
  __syncthreads();
  if (t == 0) {
    s = red[0] + red[1] + red[2] + red[3];
    ss = red[4] + red[5] + red[6] + red[7];
    float mean = s * (1.f / 65536.f);
    float var = ss * (1.f / 65536.f) - mean * mean;
    mv[0] = mean; mv[1] = rsqrtf(var + 1e-5f);
  }
  __syncthreads();
  float mean = mv[0], rstd = mv[1];
  const float* src = x + (size_t)bid * 65536;
  for (int ch = 0; ch < 16; ch++) {
#pragma unroll
    for (int i = 0; i < 4; i++) {
      int lin = t + i * 256;  // 0..1023
      int c = lin >> 4, p4 = lin & 15;
      float4 v = *(const float4*)(src + (size_t)c * 1024 + ch * 64 + p4 * 4);
      float gg = gw[g * 64 + c] * rstd;
      float bb = gb[g * 64 + c] - mean * gg;
      tile[c][p4 * 4 + 0] = v.x * gg + bb;
      tile[c][p4 * 4 + 1] = v.y * gg + bb;
      tile[c][p4 * 4 + 2] = v.z * gg + bb;
      tile[c][p4 * 4 + 3] = v.w * gg + bb;
    }
    __syncthreads();
    unsigned short* dst = xnT + ((size_t)b * 1024 + ch * 64) * 512 + g * 64;
#pragma unroll
    for (int i = 0; i < 4; i++) {
      int lin = t + i * 256;
      int pp = lin >> 4, cq = lin & 15;
      ushort4 o;
      o.x = f2bf(tile[cq * 4 + 0][pp]);
      o.y = f2bf(tile[cq * 4 + 1][pp]);
      o.z = f2bf(tile[cq * 4 + 2][pp]);
      o.w = f2bf(tile[cq * 4 + 3][pp]);
      *(ushort4*)(dst + (size_t)pp * 512 + cq * 4) = o;
    }
    __syncthreads();
  }
}

// ---------------- generic bf16 B^T GEMM: C[m,n] = sum_k A[m,k]*B[n,k] ----------------
// EPI: 0=none, 1=+bias[n], 2=+bias[m], 3=+bias[m]+res
template <int EPI, bool OUT_BF16>
__global__ __launch_bounds__(256) void gemm_bt(
    const unsigned short* __restrict__ A, int lda, long long sA,
    const unsigned short* __restrict__ B, int ldb, long long sB,
    void* __restrict__ Cv, int ldc, long long sC,
    const float* __restrict__ bias,
    const float* __restrict__ res, long long sRes,
    int M, int N, int K, int mt, int nt) {
  __shared__ __align__(16) unsigned short As[128 * 32];
  __shared__ __align__(16) unsigned short Bs[128 * 32];
  int bid = blockIdx.x;
  int per = mt * nt;
  int b = bid / per;
  int r = bid % per;
  int mi = r / nt, ni = r % nt;
  int t = threadIdx.x;
  int l = t & 63, w = t >> 6;
  int wm = w >> 1, wn = w & 1;
  int fr = l & 15;
  int fk = (l >> 4) << 3;
  const unsigned short* Ab = A + (size_t)b * sA + (size_t)(mi * 128) * lda;
  const unsigned short* Bb = B + (size_t)b * sB + (size_t)(ni * 128) * ldb;
  int sr = t >> 2, sk = (t & 3) << 3;
  const unsigned short* gA = Ab + (size_t)sr * lda + sk;
  const unsigned short* gB = Bb + (size_t)sr * ldb + sk;
  unsigned short* lA = As + w * 512;  // wave-uniform LDS dest
  unsigned short* lB = Bs + w * 512;
  const unsigned short* ra = As + (wm * 64 + fr) * 32 + fk;
  const unsigned short* rb = Bs + (wn * 64 + fr) * 32 + fk;
  f32x4 acc[4][4] = {};
  for (int k0 = 0; k0 < K; k0 += 32) {
    g2l16(gA, lA);
    g2l16(gA + (size_t)64 * lda, lA + 2048);
    g2l16(gB, lB);
    g2l16(gB + (size_t)64 * ldb, lB + 2048);
    gA += 32; gB += 32;
    __syncthreads();
    bf16x8 af[4], bv[4];
#pragma unroll
    for (int i = 0; i < 4; i++) af[i] = *(const bf16x8*)(ra + i * 512);
#pragma unroll
    for (int j = 0; j < 4; j++) bv[j] = *(const bf16x8*)(rb + j * 512);
#pragma unroll
    for (int i = 0; i < 4; i++)
#pragma unroll
      for (int j = 0; j < 4; j++)
        acc[i][j] = __builtin_amdgcn_mfma_f32_16x16x32_bf16(af[i], bv[j], acc[i][j], 0, 0, 0);
    __syncthreads();
  }
  int crow0 = mi * 128 + wm * 64;
  int ccol0 = ni * 128 + wn * 64;
  int lr = (l >> 4) << 2;
  int lc = l & 15;
#pragma unroll
  for (int i = 0; i < 4; i++) {
#pragma unroll
    for (int j = 0; j < 4; j++) {
      int col = ccol0 + j * 16 + lc;
      float bn = (EPI == 1) ? bias[col] : 0.0f;
#pragma unroll
      for (int e = 0; e < 4; e++) {
        int row = crow0 + i * 16 + lr + e;
        float v = acc[i][j][e];
        if (EPI == 1) v += bn;
        if (EPI == 2 || EPI == 3) v += bias[row];
        if (EPI == 3) v += res[(size_t)b * sRes + (size_t)row * ldc + col];
        size_t o = (size_t)b * sC + (size_t)row * ldc + col;
        if (OUT_BF16) ((unsigned short*)Cv)[o] = f2bf(v);
        else ((float*)Cv)[o] = v;
      }
    }
  }
}

// ---------------- flash attention: S=Q.K^T (K=512), online softmax, O=P.V ----------------
// grid 256 (b, i-tile of 64), 512 threads (8 waves).
// qkT[b][p][0..511]=Q, [512..1023]=K ; vbuf[b][c][p] ; obuf[b][p][c] bf16
__global__ __launch_bounds__(512) void flash_attn(
    const unsigned short* __restrict__ qkT, const unsigned short* __restrict__ vbuf,
    unsigned short* __restrict__ obuf) {
  __shared__ __align__(16) unsigned short Ks[2 * 16 * 64 * 32];  // 128KB, 2 bufs x 16 k-panels x [64j][32c]
  __shared__ __align__(16) float Slds[64 * 68];                  // 17.4KB padded
  __shared__ __align__(16) unsigned short Plds[2 * 64 * 40];     // 10.2KB, 2 j-panels x [64i][80B rows]
  __shared__ float mrow[64], lrow[64], scl[64];

  const float SC = 0.04419417382415922f;  // 1/sqrt(512)
  int bid = blockIdx.x;
  int logical = (bid & 7) * 32 + (bid >> 3);  // XCD-contiguous batches
  int b = logical >> 4, it = logical & 15;
  int i0 = it * 64;
  int tid = threadIdx.x;
  int l = tid & 63, w = tid >> 6;
  int fr = l & 15, fq = l >> 4;
  int wm2 = w >> 2;   // m-pair group (0/1): m-frags {2*wm2, 2*wm2+1}
  int nf = w & 3;     // S n-frag
  int d0 = w * 64;    // PV d-slice

  const size_t bq = (size_t)b * 1048576;
  const size_t bv = (size_t)b * 524288;

  // ---- Q fragments resident in registers: 2 m-frags x 16 k-steps ----
  const unsigned short* qr = qkT + bq + (size_t)(i0 + wm2 * 32 + fr) * 1024 + fq * 8;
  bf16x8 q[2][16];
#pragma unroll
  for (int p2 = 0; p2 < 2; p2++)
#pragma unroll
    for (int ks = 0; ks < 16; ks++)
      q[p2][ks] = *(const bf16x8*)(qr + p2 * 16384 + ks * 32);

  // ---- staging helpers ----
  int srow = (tid >> 2) & 63;
  int scc = (tid & 3) * 8;
  const unsigned short* kg0 = qkT + bq + 512 + (size_t)srow * 1024 + scc;  // + j*1024 + panel*32
  char* ldsK = (char*)Ks;

  // stage j-tile 0 into buf 0
#pragma unroll
  for (int call = 0; call < 8; call++) {
    int panel = call * 2 + (tid >> 8);
    g2l16(kg0 + (size_t)0 * 65536 + panel * 32, ldsK + call * 8192 + w * 1024);
  }
  if (tid < 64) { mrow[tid] = -3e38f; lrow[tid] = 0.f; }
  __syncthreads();  // drains vmcnt -> buf0 ready

  f32x4 acc[4][4] = {};
  const unsigned short* vb = vbuf + bv + (size_t)(d0 + fr) * 1024 + fq * 8;

  for (int jt = 0; jt < 16; jt++) {
    int cur = jt & 1;
    // ---- issue prefetch of next K tile ----
    if (jt < 15) {
      const unsigned short* kg = kg0 + (size_t)(jt + 1) * 65536;  // 64 rows * 1024
      char* dst = ldsK + (cur ^ 1) * 65536;
#pragma unroll
      for (int call = 0; call < 8; call++) {
        int panel = call * 2 + (tid >> 8);
        g2l16(kg + panel * 32, dst + call * 8192 + w * 1024);
      }
    }
    // ---- S compute: 2 m-frags x 1 n-frag, K from LDS, Q from regs ----
    {
      const char* kb = ldsK + cur * 65536 + (nf * 16 + fr) * 64 + fq * 16;
      f32x4 s0 = {0.f, 0.f, 0.f, 0.f}, s1 = {0.f, 0.f, 0.f, 0.f};
#pragma unroll
      for (int ks = 0; ks < 16; ks++) {
        bf16x8 kf = *(const bf16x8*)(kb + ks * 4096);
        s0 = __builtin_amdgcn_mfma_f32_16x16x32_bf16(q[0][ks], kf, s0, 0, 0, 0);
        s1 = __builtin_amdgcn_mfma_f32_16x16x32_bf16(q[1][ks], kf, s1, 0, 0, 0);
      }
      int col = nf * 16 + (l & 15);
      float* sp = Slds + (wm2 * 32 + fq * 4) * 68 + col;
#pragma unroll
      for (int e = 0; e < 4; e++) sp[e * 68] = s0[e];
#pragma unroll
      for (int e = 0; e < 4; e++) sp[(16 + e) * 68] = s1[e];
    }
    __syncthreads();  // S ready (also drains K prefetch)

    // ---- online softmax: 8 threads per row ----
    {
      int r = tid >> 3, s8 = tid & 7;
      const float* srowp = Slds + r * 68 + s8 * 8;
      float4 a = *(const float4*)srowp;
      float4 c = *(const float4*)(srowp + 4);
      float mx = fmaxf(fmaxf(fmaxf(a.x, a.y), fmaxf(a.z, a.w)),
                       fmaxf(fmaxf(c.x, c.y), fmaxf(c.z, c.w)));
      mx = fmaxf(mx, __shfl_xor(mx, 1, 64));
      mx = fmaxf(mx, __shfl_xor(mx, 2, 64));
      mx = fmaxf(mx, __shfl_xor(mx, 4, 64));
      float mold = mrow[r];
      float mnew = fmaxf(mold, mx);
      float e0 = __expf((a.x - mnew) * SC), e1 = __expf((a.y - mnew) * SC);
      float e2 = __expf((a.z - mnew) * SC), e3 = __expf((a.w - mnew) * SC);
      float e4 = __expf((c.x - mnew) * SC), e5 = __expf((c.y - mnew) * SC);
      float e6 = __expf((c.z - mnew) * SC), e7 = __expf((c.w - mnew) * SC);
      float sum = e0 + e1 + e2 + e3 + e4 + e5 + e6 + e7;
      sum += __shfl_xor(sum, 1, 64);
      sum += __shfl_xor(sum, 2, 64);
      sum += __shfl_xor(sum, 4, 64);
      uint4 pw;
      pw.x = f2bf(e0) | ((unsigned)f2bf(e1) << 16);
      pw.y = f2bf(e2) | ((unsigned)f2bf(e3) << 16);
      pw.z = f2bf(e4) | ((unsigned)f2bf(e5) << 16);
      pw.w = f2bf(e6) | ((unsigned)f2bf(e7) << 16);
      *(uint4*)((char*)Plds + (s8 >> 2) * 5120 + r * 80 + (s8 & 3) * 16) = pw;
      if (s8 == 0) {
        float sf = __expf((mold - mnew) * SC);
        lrow[r] = lrow[r] * sf + sum;
        mrow[r] = mnew;
        scl[r] = sf;
      }
    }
    __syncthreads();  // P + stats ready

    // ---- rescale acc, then PV: 4 m-frags x 4 n-frags x 2 k-panels ----
    {
      f32x4 sc4[4];
#pragma unroll
      for (int mi = 0; mi < 4; mi++) sc4[mi] = *(const f32x4*)(scl + mi * 16 + fq * 4);
#pragma unroll
      for (int mi = 0; mi < 4; mi++)
#pragma unroll
        for (int nj = 0; nj < 4; nj++) acc[mi][nj] *= sc4[mi];
#pragma unroll
      for (int kp = 0; kp < 2; kp++) {
        bf16x8 pf[4];
#pragma unroll
        for (int mi = 0; mi < 4; mi++)
          pf[mi] = *(const bf16x8*)((const char*)Plds + kp * 5120 + (mi * 16 + fr) * 80 + fq * 16);
#pragma unroll
        for (int nj = 0; nj < 4; nj++) {
          bf16x8 vf = *(const bf16x8*)(vb + nj * 16384 + jt * 64 + kp * 32);
#pragma unroll
          for (int mi = 0; mi < 4; mi++)
            acc[mi][nj] = __builtin_amdgcn_mfma_f32_16x16x32_bf16(pf[mi], vf, acc[mi][nj], 0, 0, 0);
        }
      }
    }
  }

  // ---- epilogue: O /= l, store bf16 ----
  f32x4 linv[4];
#pragma unroll
  for (int mi = 0; mi < 4; mi++) {
    f32x4 lv = *(const f32x4*)(lrow + mi * 16 + fq * 4);
#pragma unroll
    for (int e = 0; e < 4; e++) linv[mi][e] = 1.0f / lv[e];
  }
  unsigned short* ob = obuf + bv + (size_t)i0 * 512 + d0 + fr;
#pragma unroll
  for (int mi = 0; mi < 4; mi++)
#pragma unroll
    for (int nj = 0; nj < 4; nj++)
#pragma unroll
      for (int e = 0; e < 4; e++) {
        int row = mi * 16 + fq * 4 + e;
        ob[(size_t)row * 512 + nj * 16] = f2bf(acc[mi][nj][e] * linv[mi][e]);
      }
}

extern "C" void kernel_launch(void* const* d_in, const int* in_sizes, int n_in,
                              void* d_out, int out_size, void* d_ws, size_t ws_size,
                              hipStream_t stream) {
  const float* x = (const float*)d_in[0];
  const float* norm_w = (const float*)d_in[1];
  const float* norm_b = (const float*)d_in[2];
  const float* qkv_w = (const float*)d_in[3];
  const float* qkv_b = (const float*)d_in[4];
  const float* proj_w = (const float*)d_in[5];
  const float* proj_b = (const float*)d_in[6];
  float* out = (float*)d_out;
  char* ws = (char*)d_ws;

  size_t off = 0;
  auto alloc = [&](size_t bytes) {
    off = (off + 255) & ~(size_t)255;
    size_t r = off; off += bytes; return r;
  };
  unsigned short* wqkv  = (unsigned short*)(ws + alloc((size_t)1536 * 512 * 2));
  unsigned short* wproj = (unsigned short*)(ws + alloc((size_t)512 * 512 * 2));
  unsigned short* xnT   = (unsigned short*)(ws + alloc((size_t)16 * 1024 * 512 * 2));
  unsigned short* qkT   = (unsigned short*)(ws + alloc((size_t)16 * 1024 * 1024 * 2));
  unsigned short* vbuf  = (unsigned short*)(ws + alloc((size_t)16 * 512 * 1024 * 2));
  unsigned short* obuf  = (unsigned short*)(ws + alloc((size_t)16 * 1024 * 512 * 2));

  cvt_weights<<<4096, 256, 0, stream>>>(qkv_w, proj_w, wqkv, wproj);
  gn_fused<<<128, 256, 0, stream>>>(x, norm_w, norm_b, xnT);

  // GEMM1: qkT[b][p][o] = sum_c xnT[b][p][c] * wqkv[o][c] + qkv_b[o], o in [0,1024)
  gemm_bt<1, true><<<1024, 256, 0, stream>>>(
      xnT, 512, 1024LL * 512, wqkv, 512, 0,
      qkT, 1024, 1024LL * 1024, qkv_b, nullptr, 0, 1024, 1024, 512, 8, 8);

  // GEMM2: v[b][c][p] = sum_cc wv[c][cc] * xnT[b][p][cc] + qkv_b[1024+c]
  gemm_bt<2, true><<<512, 256, 0, stream>>>(
      wqkv + (size_t)1024 * 512, 512, 0, xnT, 512, 1024LL * 512,
      vbuf, 1024, 512LL * 1024, qkv_b + 1024, nullptr, 0, 512, 1024, 512, 4, 8);

  // fused attention: obuf[b][p][c] = softmax(Q K^T / sqrt(512)) V
  flash_attn<<<256, 512, 0, stream>>>(qkT, vbuf, obuf);

  // GEMM5: out[b][o][p] = sum_c wproj[o][c] * obuf[b][p][c] + proj_b[o] + x[b][o][p]
  gemm_bt<3, false><<<512, 256, 0, stream>>>(
      wproj, 512, 0, obuf, 512, 1024LL * 512,
      out, 1024, 512LL * 1024, proj_b, x, 512LL * 1024, 512, 1024, 512, 4, 8);
}

// Round 4
// 318.776 us; speedup vs baseline: 1.0030x; 1.0030x over previous
//
#include <hip/hip_runtime.h>
#include <stdint.h>

typedef __attribute__((ext_vector_type(4))) float f32x4;
typedef __attribute__((ext_vector_type(8))) __bf16 bf16x8;

__device__ __forceinline__ unsigned short f2bf(float f) {
  union { float f; unsigned u; } v; v.f = f;
  unsigned r = v.u + 0x7FFF + ((v.u >> 16) & 1);
  return (unsigned short)(r >> 16);
}

__device__ __forceinline__ void g2l16(const void* g, void* l) {
  __builtin_amdgcn_global_load_lds((const __attribute__((address_space(1))) void*)g,
                                   (__attribute__((address_space(3))) void*)l, 16, 0, 0);
}

// ---------------- weight fp32 -> bf16 ----------------
__global__ void cvt_weights(const float* __restrict__ a, const float* __restrict__ p,
                            unsigned short* __restrict__ wa, unsigned short* __restrict__ wp) {
  int i = blockIdx.x * 256 + threadIdx.x;
  if (i < 786432) wa[i] = f2bf(a[i]);
  else wp[i - 786432] = f2bf(p[i - 786432]);
}

// ---------------- fused groupnorm: stats + normalize + transpose ----------------
// one block per (b,g): 64 ch x 1024 px. second read is L2/L3-warm.
__global__ __launch_bounds__(256) void gn_fused(
    const float* __restrict__ x, const float* __restrict__ gw, const float* __restrict__ gb,
    unsigned short* __restrict__ xnT) {
  __shared__ float tile[64][65];
  __shared__ float red[8];
  __shared__ float mv[2];
  int bid = blockIdx.x;             // b*8+g
  int g = bid & 7, b = bid >> 3;
  int t = threadIdx.x;
  const float4* p = (const float4*)(x + (size_t)bid * 65536);
  float s = 0.f, ss = 0.f;
  for (int i = t; i < 16384; i += 256) {
    float4 v = p[i];
    s += v.x + v.y + v.z + v.w;
    ss += v.x * v.x + v.y * v.y + v.z * v.z + v.w * v.w;
  }
#pragma unroll
  for (int o = 32; o > 0; o >>= 1) {
    s += __shfl_down(s, o, 64);
    ss += __shfl_down(ss, o, 64);
  }
  int w = t >> 6;
  if ((t & 63) == 0) { red[w] = s; red[4 + w] = ss; }
  __syncthreads();
  if (t == 0) {
    s = red[0] + red[1] + red[2] + red[3];
    ss = red[4] + red[5] + red[6] + red[7];
    float mean = s * (1.f / 65536.f);
    float var = ss * (1.f / 65536.f) - mean * mean;
    mv[0] = mean; mv[1] = rsqrtf(var + 1e-5f);
  }
  __syncthreads();
  float mean = mv[0], rstd = mv[1];
  const float* src = x + (size_t)bid * 65536;
  for (int ch = 0; ch < 16; ch++) {
#pragma unroll
    for (int i = 0; i < 4; i++) {
      int lin = t + i * 256;  // 0..1023
      int c = lin >> 4, p4 = lin & 15;
      float4 v = *(const float4*)(src + (size_t)c * 1024 + ch * 64 + p4 * 4);
      float gg = gw[g * 64 + c] * rstd;
      float bb = gb[g * 64 + c] - mean * gg;
      tile[c][p4 * 4 + 0] = v.x * gg + bb;
      tile[c][p4 * 4 + 1] = v.y * gg + bb;
      tile[c][p4 * 4 + 2] = v.z * gg + bb;
      tile[c][p4 * 4 + 3] = v.w * gg + bb;
    }
    __syncthreads();
    unsigned short* dst = xnT + ((size_t)b * 1024 + ch * 64) * 512 + g * 64;
#pragma unroll
    for (int i = 0; i < 4; i++) {
      int lin = t + i * 256;
      int pp = lin >> 4, cq = lin & 15;
      ushort4 o;
      o.x = f2bf(tile[cq * 4 + 0][pp]);
      o.y = f2bf(tile[cq * 4 + 1][pp]);
      o.z = f2bf(tile[cq * 4 + 2][pp]);
      o.w = f2bf(tile[cq * 4 + 3][pp]);
      *(ushort4*)(dst + (size_t)pp * 512 + cq * 4) = o;
    }
    __syncthreads();
  }
}

// ---------------- generic bf16 B^T GEMM: C[m,n] = sum_k A[m,k]*B[n,k] ----------------
// EPI: 0=none, 1=+bias[n], 2=+bias[m], 3=+bias[m]+res
template <int EPI, bool OUT_BF16>
__global__ __launch_bounds__(256) void gemm_bt(
    const unsigned short* __restrict__ A, int lda, long long sA,
    const unsigned short* __restrict__ B, int ldb, long long sB,
    void* __restrict__ Cv, int ldc, long long sC,
    const float* __restrict__ bias,
    const float* __restrict__ res, long long sRes,
    int M, int N, int K, int mt, int nt) {
  __shared__ __align__(16) unsigned short As[128 * 32];
  __shared__ __align__(16) unsigned short Bs[128 * 32];
  int bid = blockIdx.x;
  int per = mt * nt;
  int b = bid / per;
  int r = bid % per;
  int mi = r / nt, ni = r % nt;
  int t = threadIdx.x;
  int l = t & 63, w = t >> 6;
  int wm = w >> 1, wn = w & 1;
  int fr = l & 15;
  int fk = (l >> 4) << 3;
  const unsigned short* Ab = A + (size_t)b * sA + (size_t)(mi * 128) * lda;
  const unsigned short* Bb = B + (size_t)b * sB + (size_t)(ni * 128) * ldb;
  int sr = t >> 2, sk = (t & 3) << 3;
  const unsigned short* gA = Ab + (size_t)sr * lda + sk;
  const unsigned short* gB = Bb + (size_t)sr * ldb + sk;
  unsigned short* lA = As + w * 512;  // wave-uniform LDS dest
  unsigned short* lB = Bs + w * 512;
  const unsigned short* ra = As + (wm * 64 + fr) * 32 + fk;
  const unsigned short* rb = Bs + (wn * 64 + fr) * 32 + fk;
  f32x4 acc[4][4] = {};
  for (int k0 = 0; k0 < K; k0 += 32) {
    g2l16(gA, lA);
    g2l16(gA + (size_t)64 * lda, lA + 2048);
    g2l16(gB, lB);
    g2l16(gB + (size_t)64 * ldb, lB + 2048);
    gA += 32; gB += 32;
    __syncthreads();
    bf16x8 af[4], bv[4];
#pragma unroll
    for (int i = 0; i < 4; i++) af[i] = *(const bf16x8*)(ra + i * 512);
#pragma unroll
    for (int j = 0; j < 4; j++) bv[j] = *(const bf16x8*)(rb + j * 512);
#pragma unroll
    for (int i = 0; i < 4; i++)
#pragma unroll
      for (int j = 0; j < 4; j++)
        acc[i][j] = __builtin_amdgcn_mfma_f32_16x16x32_bf16(af[i], bv[j], acc[i][j], 0, 0, 0);
    __syncthreads();
  }
  int crow0 = mi * 128 + wm * 64;
  int ccol0 = ni * 128 + wn * 64;
  int lr = (l >> 4) << 2;
  int lc = l & 15;
#pragma unroll
  for (int i = 0; i < 4; i++) {
#pragma unroll
    for (int j = 0; j < 4; j++) {
      int col = ccol0 + j * 16 + lc;
      float bn = (EPI == 1) ? bias[col] : 0.0f;
#pragma unroll
      for (int e = 0; e < 4; e++) {
        int row = crow0 + i * 16 + lr + e;
        float v = acc[i][j][e];
        if (EPI == 1) v += bn;
        if (EPI == 2 || EPI == 3) v += bias[row];
        if (EPI == 3) v += res[(size_t)b * sRes + (size_t)row * ldc + col];
        size_t o = (size_t)b * sC + (size_t)row * ldc + col;
        if (OUT_BF16) ((unsigned short*)Cv)[o] = f2bf(v);
        else ((float*)Cv)[o] = v;
      }
    }
  }
}

// ---------------- flash attention: S=Q.K^T (K=512), online softmax, O=P.V ----------------
// grid 256 (b, i-tile of 64), 512 threads (8 waves).
// qkT[b][p][0..511]=Q, [512..1023]=K ; vbuf[b][c][p] ; obuf[b][p][c] bf16
// __launch_bounds__(512, 2): min 2 waves/EU -> 256 VGPR cap, so q[2][16]
// (128 VGPR) stays RESIDENT. LDS is 156KB -> 1 block/CU either way, so
// allowing 256 VGPR costs no occupancy.
__global__ __launch_bounds__(512, 2) void flash_attn(
    const unsigned short* __restrict__ qkT, const unsigned short* __restrict__ vbuf,
    unsigned short* __restrict__ obuf) {
  __shared__ __align__(16) unsigned short Ks[2 * 16 * 64 * 32];  // 128KB, 2 bufs x 16 k-panels x [64j][32c]
  __shared__ __align__(16) float Slds[64 * 68];                  // 17.4KB padded
  __shared__ __align__(16) unsigned short Plds[2 * 64 * 40];     // 10.2KB, 2 j-panels x [64i][80B rows]
  __shared__ float mrow[64], lrow[64], scl[64];

  const float SC = 0.04419417382415922f;  // 1/sqrt(512)
  int bid = blockIdx.x;
  int logical = (bid & 7) * 32 + (bid >> 3);  // XCD-contiguous batches
  int b = logical >> 4, it = logical & 15;
  int i0 = it * 64;
  int tid = threadIdx.x;
  int l = tid & 63, w = tid >> 6;
  int fr = l & 15, fq = l >> 4;
  int wm2 = w >> 2;   // m-pair group (0/1): m-frags {2*wm2, 2*wm2+1}
  int nf = w & 3;     // S n-frag
  int d0 = w * 64;    // PV d-slice

  const size_t bq = (size_t)b * 1048576;
  const size_t bv = (size_t)b * 524288;

  // ---- Q fragments resident in registers: 2 m-frags x 16 k-steps ----
  const unsigned short* qr = qkT + bq + (size_t)(i0 + wm2 * 32 + fr) * 1024 + fq * 8;
  bf16x8 q[2][16];
#pragma unroll
  for (int p2 = 0; p2 < 2; p2++)
#pragma unroll
    for (int ks = 0; ks < 16; ks++)
      q[p2][ks] = *(const bf16x8*)(qr + p2 * 16384 + ks * 32);

  // ---- staging helpers ----
  int srow = (tid >> 2) & 63;
  int scc = (tid & 3) * 8;
  const unsigned short* kg0 = qkT + bq + 512 + (size_t)srow * 1024 + scc;  // + j*1024 + panel*32
  char* ldsK = (char*)Ks;

  // stage j-tile 0 into buf 0
#pragma unroll
  for (int call = 0; call < 8; call++) {
    int panel = call * 2 + (tid >> 8);
    g2l16(kg0 + (size_t)0 * 65536 + panel * 32, ldsK + call * 8192 + w * 1024);
  }
  if (tid < 64) { mrow[tid] = -3e38f; lrow[tid] = 0.f; }
  __syncthreads();  // drains vmcnt -> buf0 ready

  f32x4 acc[4][4] = {};
  const unsigned short* vb = vbuf + bv + (size_t)(d0 + fr) * 1024 + fq * 8;

  for (int jt = 0; jt < 16; jt++) {
    int cur = jt & 1;
    // ---- issue prefetch of next K tile ----
    if (jt < 15) {
      const unsigned short* kg = kg0 + (size_t)(jt + 1) * 65536;  // 64 rows * 1024
      char* dst = ldsK + (cur ^ 1) * 65536;
#pragma unroll
      for (int call = 0; call < 8; call++) {
        int panel = call * 2 + (tid >> 8);
        g2l16(kg + panel * 32, dst + call * 8192 + w * 1024);
      }
    }
    // ---- S compute: 2 m-frags x 1 n-frag, K from LDS, Q from regs ----
    {
      const char* kb = ldsK + cur * 65536 + (nf * 16 + fr) * 64 + fq * 16;
      f32x4 s0 = {0.f, 0.f, 0.f, 0.f}, s1 = {0.f, 0.f, 0.f, 0.f};
#pragma unroll
      for (int ks = 0; ks < 16; ks++) {
        bf16x8 kf = *(const bf16x8*)(kb + ks * 4096);
        s0 = __builtin_amdgcn_mfma_f32_16x16x32_bf16(q[0][ks], kf, s0, 0, 0, 0);
        s1 = __builtin_amdgcn_mfma_f32_16x16x32_bf16(q[1][ks], kf, s1, 0, 0, 0);
      }
      int col = nf * 16 + (l & 15);
      float* sp = Slds + (wm2 * 32 + fq * 4) * 68 + col;
#pragma unroll
      for (int e = 0; e < 4; e++) sp[e * 68] = s0[e];
#pragma unroll
      for (int e = 0; e < 4; e++) sp[(16 + e) * 68] = s1[e];
    }
    __syncthreads();  // S ready (also drains K prefetch)

    // ---- online softmax: 8 threads per row ----
    {
      int r = tid >> 3, s8 = tid & 7;
      const float* srowp = Slds + r * 68 + s8 * 8;
      float4 a = *(const float4*)srowp;
      float4 c = *(const float4*)(srowp + 4);
      float mx = fmaxf(fmaxf(fmaxf(a.x, a.y), fmaxf(a.z, a.w)),
                       fmaxf(fmaxf(c.x, c.y), fmaxf(c.z, c.w)));
      mx = fmaxf(mx, __shfl_xor(mx, 1, 64));
      mx = fmaxf(mx, __shfl_xor(mx, 2, 64));
      mx = fmaxf(mx, __shfl_xor(mx, 4, 64));
      float mold = mrow[r];
      float mnew = fmaxf(mold, mx);
      float e0 = __expf((a.x - mnew) * SC), e1 = __expf((a.y - mnew) * SC);
      float e2 = __expf((a.z - mnew) * SC), e3 = __expf((a.w - mnew) * SC);
      float e4 = __expf((c.x - mnew) * SC), e5 = __expf((c.y - mnew) * SC);
      float e6 = __expf((c.z - mnew) * SC), e7 = __expf((c.w - mnew) * SC);
      float sum = e0 + e1 + e2 + e3 + e4 + e5 + e6 + e7;
      sum += __shfl_xor(sum, 1, 64);
      sum += __shfl_xor(sum, 2, 64);
      sum += __shfl_xor(sum, 4, 64);
      uint4 pw;
      pw.x = f2bf(e0) | ((unsigned)f2bf(e1) << 16);
      pw.y = f2bf(e2) | ((unsigned)f2bf(e3) << 16);
      pw.z = f2bf(e4) | ((unsigned)f2bf(e5) << 16);
      pw.w = f2bf(e6) | ((unsigned)f2bf(e7) << 16);
      *(uint4*)((char*)Plds + (s8 >> 2) * 5120 + r * 80 + (s8 & 3) * 16) = pw;
      if (s8 == 0) {
        float sf = __expf((mold - mnew) * SC);
        lrow[r] = lrow[r] * sf + sum;
        mrow[r] = mnew;
        scl[r] = sf;
      }
    }
    __syncthreads();  // P + stats ready

    // ---- rescale acc, then PV: 4 m-frags x 4 n-frags x 2 k-panels ----
    {
      f32x4 sc4[4];
#pragma unroll
      for (int mi = 0; mi < 4; mi++) sc4[mi] = *(const f32x4*)(scl + mi * 16 + fq * 4);
#pragma unroll
      for (int mi = 0; mi < 4; mi++)
#pragma unroll
        for (int nj = 0; nj < 4; nj++) acc[mi][nj] *= sc4[mi];
#pragma unroll
      for (int kp = 0; kp < 2; kp++) {
        bf16x8 pf[4];
#pragma unroll
        for (int mi = 0; mi < 4; mi++)
          pf[mi] = *(const bf16x8*)((const char*)Plds + kp * 5120 + (mi * 16 + fr) * 80 + fq * 16);
#pragma unroll
        for (int nj = 0; nj < 4; nj++) {
          bf16x8 vf = *(const bf16x8*)(vb + nj * 16384 + jt * 64 + kp * 32);
#pragma unroll
          for (int mi = 0; mi < 4; mi++)
            acc[mi][nj] = __builtin_amdgcn_mfma_f32_16x16x32_bf16(pf[mi], vf, acc[mi][nj], 0, 0, 0);
        }
      }
    }
  }

  // ---- epilogue: O /= l, store bf16 ----
  f32x4 linv[4];
#pragma unroll
  for (int mi = 0; mi < 4; mi++) {
    f32x4 lv = *(const f32x4*)(lrow + mi * 16 + fq * 4);
#pragma unroll
    for (int e = 0; e < 4; e++) linv[mi][e] = 1.0f / lv[e];
  }
  unsigned short* ob = obuf + bv + (size_t)i0 * 512 + d0 + fr;
#pragma unroll
  for (int mi = 0; mi < 4; mi++)
#pragma unroll
    for (int nj = 0; nj < 4; nj++)
#pragma unroll
      for (int e = 0; e < 4; e++) {
        int row = mi * 16 + fq * 4 + e;
        ob[(size_t)row * 512 + nj * 16] = f2bf(acc[mi][nj][e] * linv[mi][e]);
      }
}

extern "C" void kernel_launch(void* const* d_in, const int* in_sizes, int n_in,
                              void* d_out, int out_size, void* d_ws, size_t ws_size,
                              hipStream_t stream) {
  const float* x = (const float*)d_in[0];
  const float* norm_w = (const float*)d_in[1];
  const float* norm_b = (const float*)d_in[2];
  const float* qkv_w = (const float*)d_in[3];
  const float* qkv_b = (const float*)d_in[4];
  const float* proj_w = (const float*)d_in[5];
  const float* proj_b = (const float*)d_in[6];
  float* out = (float*)d_out;
  char* ws = (char*)d_ws;

  size_t off = 0;
  auto alloc = [&](size_t bytes) {
    off = (off + 255) & ~(size_t)255;
    size_t r = off; off += bytes; return r;
  };
  unsigned short* wqkv  = (unsigned short*)(ws + alloc((size_t)1536 * 512 * 2));
  unsigned short* wproj = (unsigned short*)(ws + alloc((size_t)512 * 512 * 2));
  unsigned short* xnT   = (unsigned short*)(ws + alloc((size_t)16 * 1024 * 512 * 2));
  unsigned short* qkT   = (unsigned short*)(ws + alloc((size_t)16 * 1024 * 1024 * 2));
  unsigned short* vbuf  = (unsigned short*)(ws + alloc((size_t)16 * 512 * 1024 * 2));
  unsigned short* obuf  = (unsigned short*)(ws + alloc((size_t)16 * 1024 * 512 * 2));

  cvt_weights<<<4096, 256, 0, stream>>>(qkv_w, proj_w, wqkv, wproj);
  gn_fused<<<128, 256, 0, stream>>>(x, norm_w, norm_b, xnT);

  // GEMM1: qkT[b][p][o] = sum_c xnT[b][p][c] * wqkv[o][c] + qkv_b[o], o in [0,1024)
  gemm_bt<1, true><<<1024, 256, 0, stream>>>(
      xnT, 512, 1024LL * 512, wqkv, 512, 0,
      qkT, 1024, 1024LL * 1024, qkv_b, nullptr, 0, 1024, 1024, 512, 8, 8);

  // GEMM2: v[b][c][p] = sum_cc wv[c][cc] * xnT[b][p][cc] + qkv_b[1024+c]
  gemm_bt<2, true><<<512, 256, 0, stream>>>(
      wqkv + (size_t)1024 * 512, 512, 0, xnT, 512, 1024LL * 512,
      vbuf, 1024, 512LL * 1024, qkv_b + 1024, nullptr, 0, 512, 1024, 512, 4, 8);

  // fused attention: obuf[b][p][c] = softmax(Q K^T / sqrt(512)) V
  flash_attn<<<256, 512, 0, stream>>>(qkT, vbuf, obuf);

  // GEMM5: out[b][o][p] = sum_c wproj[o][c] * obuf[b][p][c] + proj_b[o] + x[b][o][p]
  gemm_bt<3, false><<<512, 256, 0, stream>>>(
      wproj, 512, 0, obuf, 512, 1024LL * 512,
      out, 1024, 512LL * 1024, proj_b, x, 512LL * 1024, 512, 1024, 512, 4, 8);
}

// Round 5
// 287.778 us; speedup vs baseline: 1.1111x; 1.1077x over previous
//
#include <hip/hip_runtime.h>
#include <stdint.h>

typedef __attribute__((ext_vector_type(4))) float f32x4;
typedef __attribute__((ext_vector_type(8))) __bf16 bf16x8;

__device__ __forceinline__ unsigned short f2bf(float f) {
  union { float f; unsigned u; } v; v.f = f;
  unsigned r = v.u + 0x7FFF + ((v.u >> 16) & 1);
  return (unsigned short)(r >> 16);
}

__device__ __forceinline__ void g2l16(const void* g, void* l) {
  __builtin_amdgcn_global_load_lds((const __attribute__((address_space(1))) void*)g,
                                   (__attribute__((address_space(3))) void*)l, 16, 0, 0);
}

// ---------------- weight fp32 -> bf16 ----------------
__global__ void cvt_weights(const float* __restrict__ a, const float* __restrict__ p,
                            unsigned short* __restrict__ wa, unsigned short* __restrict__ wp) {
  int i = blockIdx.x * 256 + threadIdx.x;
  if (i < 786432) wa[i] = f2bf(a[i]);
  else wp[i - 786432] = f2bf(p[i - 786432]);
}

// ---------------- fused groupnorm: stats + normalize + transpose ----------------
__global__ __launch_bounds__(256) void gn_fused(
    const float* __restrict__ x, const float* __restrict__ gw, const float* __restrict__ gb,
    unsigned short* __restrict__ xnT) {
  __shared__ float tile[64][65];
  __shared__ float red[8];
  __shared__ float mv[2];
  int bid = blockIdx.x;             // b*8+g
  int g = bid & 7, b = bid >> 3;
  int t = threadIdx.x;
  const float4* p = (const float4*)(x + (size_t)bid * 65536);
  float s = 0.f, ss = 0.f;
  for (int i = t; i < 16384; i += 256) {
    float4 v = p[i];
    s += v.x + v.y + v.z + v.w;
    ss += v.x * v.x + v.y * v.y + v.z * v.z + v.w * v.w;
  }
#pragma unroll
  for (int o = 32; o > 0; o >>= 1) {
    s += __shfl_down(s, o, 64);
    ss += __shfl_down(ss, o, 64);
  }
  int w = t >> 6;
  if ((t & 63) == 0) { red[w] = s; red[4 + w] = ss; }
  __syncthreads();
  if (t == 0) {
    s = red[0] + red[1] + red[2] + red[3];
    ss = red[4] + red[5] + red[6] + red[7];
    float mean = s * (1.f / 65536.f);
    float var = ss * (1.f / 65536.f) - mean * mean;
    mv[0] = mean; mv[1] = rsqrtf(var + 1e-5f);
  }
  __syncthreads();
  float mean = mv[0], rstd = mv[1];
  const float* src = x + (size_t)bid * 65536;
  for (int ch = 0; ch < 16; ch++) {
#pragma unroll
    for (int i = 0; i < 4; i++) {
      int lin = t + i * 256;  // 0..1023
      int c = lin >> 4, p4 = lin & 15;
      float4 v = *(const float4*)(src + (size_t)c * 1024 + ch * 64 + p4 * 4);
      float gg = gw[g * 64 + c] * rstd;
      float bb = gb[g * 64 + c] - mean * gg;
      tile[c][p4 * 4 + 0] = v.x * gg + bb;
      tile[c][p4 * 4 + 1] = v.y * gg + bb;
      tile[c][p4 * 4 + 2] = v.z * gg + bb;
      tile[c][p4 * 4 + 3] = v.w * gg + bb;
    }
    __syncthreads();
    unsigned short* dst = xnT + ((size_t)b * 1024 + ch * 64) * 512 + g * 64;
#pragma unroll
    for (int i = 0; i < 4; i++) {
      int lin = t + i * 256;
      int pp = lin >> 4, cq = lin & 15;
      ushort4 o;
      o.x = f2bf(tile[cq * 4 + 0][pp]);
      o.y = f2bf(tile[cq * 4 + 1][pp]);
      o.z = f2bf(tile[cq * 4 + 2][pp]);
      o.w = f2bf(tile[cq * 4 + 3][pp]);
      *(ushort4*)(dst + (size_t)pp * 512 + cq * 4) = o;
    }
    __syncthreads();
  }
}

// ---------------- generic bf16 B^T GEMM: C[m,n] = sum_k A[m,k]*B[n,k] ----------------
// EPI: 0=none, 1=+bias[n], 2=+bias[m], 3=+bias[m]+res
template <int EPI, bool OUT_BF16>
__global__ __launch_bounds__(256) void gemm_bt(
    const unsigned short* __restrict__ A, int lda, long long sA,
    const unsigned short* __restrict__ B, int ldb, long long sB,
    void* __restrict__ Cv, int ldc, long long sC,
    const float* __restrict__ bias,
    const float* __restrict__ res, long long sRes,
    int M, int N, int K, int mt, int nt) {
  __shared__ __align__(16) unsigned short As[128 * 32];
  __shared__ __align__(16) unsigned short Bs[128 * 32];
  int bid = blockIdx.x;
  int per = mt * nt;
  int b = bid / per;
  int r = bid % per;
  int mi = r / nt, ni = r % nt;
  int t = threadIdx.x;
  int l = t & 63, w = t >> 6;
  int wm = w >> 1, wn = w & 1;
  int fr = l & 15;
  int fk = (l >> 4) << 3;
  const unsigned short* Ab = A + (size_t)b * sA + (size_t)(mi * 128) * lda;
  const unsigned short* Bb = B + (size_t)b * sB + (size_t)(ni * 128) * ldb;
  int sr = t >> 2, sk = (t & 3) << 3;
  const unsigned short* gA = Ab + (size_t)sr * lda + sk;
  const unsigned short* gB = Bb + (size_t)sr * ldb + sk;
  unsigned short* lA = As + w * 512;  // wave-uniform LDS dest
  unsigned short* lB = Bs + w * 512;
  const unsigned short* ra = As + (wm * 64 + fr) * 32 + fk;
  const unsigned short* rb = Bs + (wn * 64 + fr) * 32 + fk;
  f32x4 acc[4][4] = {};
  for (int k0 = 0; k0 < K; k0 += 32) {
    g2l16(gA, lA);
    g2l16(gA + (size_t)64 * lda, lA + 2048);
    g2l16(gB, lB);
    g2l16(gB + (size_t)64 * ldb, lB + 2048);
    gA += 32; gB += 32;
    __syncthreads();
    bf16x8 af[4], bv[4];
#pragma unroll
    for (int i = 0; i < 4; i++) af[i] = *(const bf16x8*)(ra + i * 512);
#pragma unroll
    for (int j = 0; j < 4; j++) bv[j] = *(const bf16x8*)(rb + j * 512);
#pragma unroll
    for (int i = 0; i < 4; i++)
#pragma unroll
      for (int j = 0; j < 4; j++)
        acc[i][j] = __builtin_amdgcn_mfma_f32_16x16x32_bf16(af[i], bv[j], acc[i][j], 0, 0, 0);
    __syncthreads();
  }
  int crow0 = mi * 128 + wm * 64;
  int ccol0 = ni * 128 + wn * 64;
  int lr = (l >> 4) << 2;
  int lc = l & 15;
#pragma unroll
  for (int i = 0; i < 4; i++) {
#pragma unroll
    for (int j = 0; j < 4; j++) {
      int col = ccol0 + j * 16 + lc;
      float bn = (EPI == 1) ? bias[col] : 0.0f;
#pragma unroll
      for (int e = 0; e < 4; e++) {
        int row = crow0 + i * 16 + lr + e;
        float v = acc[i][j][e];
        if (EPI == 1) v += bn;
        if (EPI == 2 || EPI == 3) v += bias[row];
        if (EPI == 3) v += res[(size_t)b * sRes + (size_t)row * ldc + col];
        size_t o = (size_t)b * sC + (size_t)row * ldc + col;
        if (OUT_BF16) ((unsigned short*)Cv)[o] = f2bf(v);
        else ((float*)Cv)[o] = v;
      }
    }
  }
}

// ---------------- flash attention v3: Q in LDS, K/V direct from L2, KVBLK=128 ----------------
// grid 256 (b, i-tile of 64 rows), 512 threads (8 waves).
// qkT[b][p][0..511]=Q, [512..1023]=K ; vbuf[b][c][p] ; obuf[b][p][c] bf16
// Wave w owns: S stripe cols w*16..w*16+15 (all 64 rows), PV d-slice w*64..w*64+63.
__global__ __launch_bounds__(512, 1) void flash_attn(
    const unsigned short* __restrict__ qkT, const unsigned short* __restrict__ vbuf,
    unsigned short* __restrict__ obuf) {
  // Q rows padded to 1040B: row-stride = 260 words ≡ 4 (mod 32) -> 2-way bank alias (free).
  // Legal with global_load_lds: each call stages exactly one 1024B row (wave-uniform base).
  __shared__ __align__(16) unsigned short Qs[64 * 520];       // 66.6 KB
  __shared__ __align__(16) float Slds[64 * 132];              // 33.8 KB
  __shared__ __align__(16) unsigned short Plds[4 * 64 * 40];  // 20.5 KB: 4 kp-panels x [64r][80B]
  __shared__ float mrow[64], lrow[64], scl[64];

  const float SC = 0.04419417382415922f;  // 1/sqrt(512)
  int bid = blockIdx.x;
  int logical = (bid & 7) * 32 + (bid >> 3);  // 2 batches per XCD -> K+V L2-resident
  int b = logical >> 4, it = logical & 15;
  int i0 = it * 64;
  int tid = threadIdx.x;
  int l = tid & 63, w = tid >> 6;
  int fr = l & 15, fq = l >> 4;
  int d0 = w * 64;

  const size_t bq = (size_t)b * 1048576;
  const size_t bv = (size_t)b * 524288;

  // ---- stage Q once: call i stages rows i*8..i*8+7 (one row per wave) ----
  {
    const unsigned short* qsrc = qkT + bq + (size_t)i0 * 1024 + l * 8;
#pragma unroll
    for (int i = 0; i < 8; i++) {
      int row = i * 8 + w;
      g2l16(qsrc + (size_t)row * 1024, (char*)Qs + row * 1040);
    }
  }
  if (tid < 64) { mrow[tid] = -3e38f; lrow[tid] = 0.f; }
  __syncthreads();  // drains vmcnt -> Q ready

  f32x4 acc[4][4] = {};
  const unsigned short* kg = qkT + bq + 512 + (size_t)(w * 16 + fr) * 1024 + fq * 8;
  const unsigned short* vg = vbuf + bv + (size_t)(d0 + fr) * 1024 + fq * 8;

  for (int jt = 0; jt < 8; jt++) {
    // ---- S phase: 4 m-frags x 1 n-frag(wave stripe), Q from LDS, K from global(L2) ----
    {
      const unsigned short* kgj = kg + (size_t)jt * 131072;  // 128 rows * 1024
      f32x4 sacc[4] = {};
#pragma unroll
      for (int ks = 0; ks < 16; ks++) {
        bf16x8 kf = *(const bf16x8*)(kgj + ks * 32);
#pragma unroll
        for (int mi = 0; mi < 4; mi++) {
          bf16x8 qa = *(const bf16x8*)((const char*)Qs + (mi * 16 + fr) * 1040 + (ks * 4 + fq) * 16);
          sacc[mi] = __builtin_amdgcn_mfma_f32_16x16x32_bf16(qa, kf, sacc[mi], 0, 0, 0);
        }
      }
#pragma unroll
      for (int mi = 0; mi < 4; mi++) {
        float* sp = Slds + (mi * 16 + fq * 4) * 132 + w * 16 + fr;
#pragma unroll
        for (int e = 0; e < 4; e++) sp[e * 132] = sacc[mi][e];
      }
    }
    __syncthreads();  // S visible

    // ---- online softmax: 8 threads/row x 16 cols each ----
    {
      int r = tid >> 3, s8 = tid & 7;
      const float* srowp = Slds + r * 132 + s8 * 16;
      float4 a0 = *(const float4*)(srowp + 0);
      float4 a1 = *(const float4*)(srowp + 4);
      float4 a2 = *(const float4*)(srowp + 8);
      float4 a3 = *(const float4*)(srowp + 12);
      float mx = fmaxf(fmaxf(fmaxf(a0.x, a0.y), fmaxf(a0.z, a0.w)),
                       fmaxf(fmaxf(a1.x, a1.y), fmaxf(a1.z, a1.w)));
      mx = fmaxf(mx, fmaxf(fmaxf(fmaxf(a2.x, a2.y), fmaxf(a2.z, a2.w)),
                           fmaxf(fmaxf(a3.x, a3.y), fmaxf(a3.z, a3.w))));
      mx = fmaxf(mx, __shfl_xor(mx, 1, 64));
      mx = fmaxf(mx, __shfl_xor(mx, 2, 64));
      mx = fmaxf(mx, __shfl_xor(mx, 4, 64));
      float mold = mrow[r];
      float mnew = fmaxf(mold, mx);
      float e0 = __expf((a0.x - mnew) * SC), e1 = __expf((a0.y - mnew) * SC);
      float e2 = __expf((a0.z - mnew) * SC), e3 = __expf((a0.w - mnew) * SC);
      float e4 = __expf((a1.x - mnew) * SC), e5 = __expf((a1.y - mnew) * SC);
      float e6 = __expf((a1.z - mnew) * SC), e7 = __expf((a1.w - mnew) * SC);
      float e8 = __expf((a2.x - mnew) * SC), e9 = __expf((a2.y - mnew) * SC);
      float ea = __expf((a2.z - mnew) * SC), eb = __expf((a2.w - mnew) * SC);
      float ec = __expf((a3.x - mnew) * SC), ed = __expf((a3.y - mnew) * SC);
      float ee = __expf((a3.z - mnew) * SC), ef = __expf((a3.w - mnew) * SC);
      float sum = ((e0 + e1) + (e2 + e3)) + ((e4 + e5) + (e6 + e7)) +
                  ((e8 + e9) + (ea + eb)) + ((ec + ed) + (ee + ef));
      sum += __shfl_xor(sum, 1, 64);
      sum += __shfl_xor(sum, 2, 64);
      sum += __shfl_xor(sum, 4, 64);
      uint4 pw0, pw1;
      pw0.x = f2bf(e0) | ((unsigned)f2bf(e1) << 16);
      pw0.y = f2bf(e2) | ((unsigned)f2bf(e3) << 16);
      pw0.z = f2bf(e4) | ((unsigned)f2bf(e5) << 16);
      pw0.w = f2bf(e6) | ((unsigned)f2bf(e7) << 16);
      pw1.x = f2bf(e8) | ((unsigned)f2bf(e9) << 16);
      pw1.y = f2bf(ea) | ((unsigned)f2bf(eb) << 16);
      pw1.z = f2bf(ec) | ((unsigned)f2bf(ed) << 16);
      pw1.w = f2bf(ee) | ((unsigned)f2bf(ef) << 16);
      char* pp = (char*)Plds + (s8 >> 1) * 5120 + r * 80 + (s8 & 1) * 32;
      *(uint4*)pp = pw0;
      *(uint4*)(pp + 16) = pw1;
      if (s8 == 0) {
        float sf = __expf((mold - mnew) * SC);
        lrow[r] = lrow[r] * sf + sum;
        mrow[r] = mnew;
        scl[r] = sf;
      }
    }
    __syncthreads();  // P + stats visible (next S-phase overlaps PV, no 3rd barrier)

    // ---- rescale acc, then PV: 4 m x 4 n x 4 kp, V from global(L2) ----
    {
      f32x4 sc4[4];
#pragma unroll
      for (int mi = 0; mi < 4; mi++) sc4[mi] = *(const f32x4*)(scl + mi * 16 + fq * 4);
#pragma unroll
      for (int mi = 0; mi < 4; mi++)
#pragma unroll
        for (int nj = 0; nj < 4; nj++) acc[mi][nj] *= sc4[mi];
      const unsigned short* vgj = vg + jt * 128;
#pragma unroll
      for (int kp = 0; kp < 4; kp++) {
        bf16x8 pf[4];
#pragma unroll
        for (int mi = 0; mi < 4; mi++)
          pf[mi] = *(const bf16x8*)((const char*)Plds + kp * 5120 + (mi * 16 + fr) * 80 + fq * 16);
#pragma unroll
        for (int nj = 0; nj < 4; nj++) {
          bf16x8 vf = *(const bf16x8*)(vgj + nj * 16384 + kp * 32);
#pragma unroll
          for (int mi = 0; mi < 4; mi++)
            acc[mi][nj] = __builtin_amdgcn_mfma_f32_16x16x32_bf16(pf[mi], vf, acc[mi][nj], 0, 0, 0);
        }
      }
    }
  }

  // ---- epilogue: O /= l, store bf16 ----
  f32x4 linv[4];
#pragma unroll
  for (int mi = 0; mi < 4; mi++) {
    f32x4 lv = *(const f32x4*)(lrow + mi * 16 + fq * 4);
#pragma unroll
    for (int e = 0; e < 4; e++) linv[mi][e] = 1.0f / lv[e];
  }
  unsigned short* ob = obuf + bv + (size_t)i0 * 512 + d0 + fr;
#pragma unroll
  for (int mi = 0; mi < 4; mi++)
#pragma unroll
    for (int nj = 0; nj < 4; nj++)
#pragma unroll
      for (int e = 0; e < 4; e++) {
        int row = mi * 16 + fq * 4 + e;
        ob[(size_t)row * 512 + nj * 16] = f2bf(acc[mi][nj][e] * linv[mi][e]);
      }
}

extern "C" void kernel_launch(void* const* d_in, const int* in_sizes, int n_in,
                              void* d_out, int out_size, void* d_ws, size_t ws_size,
                              hipStream_t stream) {
  const float* x = (const float*)d_in[0];
  const float* norm_w = (const float*)d_in[1];
  const float* norm_b = (const float*)d_in[2];
  const float* qkv_w = (const float*)d_in[3];
  const float* qkv_b = (const float*)d_in[4];
  const float* proj_w = (const float*)d_in[5];
  const float* proj_b = (const float*)d_in[6];
  float* out = (float*)d_out;
  char* ws = (char*)d_ws;

  size_t off = 0;
  auto alloc = [&](size_t bytes) {
    off = (off + 255) & ~(size_t)255;
    size_t r = off; off += bytes; return r;
  };
  unsigned short* wqkv  = (unsigned short*)(ws + alloc((size_t)1536 * 512 * 2));
  unsigned short* wproj = (unsigned short*)(ws + alloc((size_t)512 * 512 * 2));
  unsigned short* xnT   = (unsigned short*)(ws + alloc((size_t)16 * 1024 * 512 * 2));
  unsigned short* qkT   = (unsigned short*)(ws + alloc((size_t)16 * 1024 * 1024 * 2));
  unsigned short* vbuf  = (unsigned short*)(ws + alloc((size_t)16 * 512 * 1024 * 2));
  unsigned short* obuf  = (unsigned short*)(ws + alloc((size_t)16 * 1024 * 512 * 2));

  cvt_weights<<<4096, 256, 0, stream>>>(qkv_w, proj_w, wqkv, wproj);
  gn_fused<<<128, 256, 0, stream>>>(x, norm_w, norm_b, xnT);

  // GEMM1: qkT[b][p][o] = sum_c xnT[b][p][c] * wqkv[o][c] + qkv_b[o], o in [0,1024)
  gemm_bt<1, true><<<1024, 256, 0, stream>>>(
      xnT, 512, 1024LL * 512, wqkv, 512, 0,
      qkT, 1024, 1024LL * 1024, qkv_b, nullptr, 0, 1024, 1024, 512, 8, 8);

  // GEMM2: v[b][c][p] = sum_cc wv[c][cc] * xnT[b][p][cc] + qkv_b[1024+c]
  gemm_bt<2, true><<<512, 256, 0, stream>>>(
      wqkv + (size_t)1024 * 512, 512, 0, xnT, 512, 1024LL * 512,
      vbuf, 1024, 512LL * 1024, qkv_b + 1024, nullptr, 0, 512, 1024, 512, 4, 8);

  // fused attention: obuf[b][p][c] = softmax(Q K^T / sqrt(512)) V
  flash_attn<<<256, 512, 0, stream>>>(qkT, vbuf, obuf);

  // GEMM5: out[b][o][p] = sum_c wproj[o][c] * obuf[b][p][c] + proj_b[o] + x[b][o][p]
  gemm_bt<3, false><<<512, 256, 0, stream>>>(
      wproj, 512, 0, obuf, 512, 1024LL * 512,
      out, 1024, 512LL * 1024, proj_b, x, 512LL * 1024, 512, 1024, 512, 4, 8);
}

// Round 7
// 285.329 us; speedup vs baseline: 1.1206x; 1.0086x over previous
//
#include <hip/hip_runtime.h>
#include <stdint.h>

typedef __attribute__((ext_vector_type(4))) float f32x4;
typedef __attribute__((ext_vector_type(8))) __bf16 bf16x8;

__device__ __forceinline__ unsigned short f2bf(float f) {
  union { float f; unsigned u; } v; v.f = f;
  unsigned r = v.u + 0x7FFF + ((v.u >> 16) & 1);
  return (unsigned short)(r >> 16);
}

__device__ __forceinline__ void g2l16(const void* g, void* l) {
  __builtin_amdgcn_global_load_lds((const __attribute__((address_space(1))) void*)g,
                                   (__attribute__((address_space(3))) void*)l, 16, 0, 0);
}

// ---------------- weight fp32 -> bf16 ----------------
__global__ void cvt_weights(const float* __restrict__ a, const float* __restrict__ p,
                            unsigned short* __restrict__ wa, unsigned short* __restrict__ wp) {
  int i = blockIdx.x * 256 + threadIdx.x;
  if (i < 786432) wa[i] = f2bf(a[i]);
  else wp[i - 786432] = f2bf(p[i - 786432]);
}

// ---------------- fused groupnorm: stats + normalize + transpose ----------------
__global__ __launch_bounds__(256) void gn_fused(
    const float* __restrict__ x, const float* __restrict__ gw, const float* __restrict__ gb,
    unsigned short* __restrict__ xnT) {
  __shared__ float tile[64][65];
  __shared__ float red[8];
  __shared__ float mv[2];
  int bid = blockIdx.x;             // b*8+g
  int g = bid & 7, b = bid >> 3;
  int t = threadIdx.x;
  const float4* p = (const float4*)(x + (size_t)bid * 65536);
  float s = 0.f, ss = 0.f;
  for (int i = t; i < 16384; i += 256) {
    float4 v = p[i];
    s += v.x + v.y + v.z + v.w;
    ss += v.x * v.x + v.y * v.y + v.z * v.z + v.w * v.w;
  }
#pragma unroll
  for (int o = 32; o > 0; o >>= 1) {
    s += __shfl_down(s, o, 64);
    ss += __shfl_down(ss, o, 64);
  }
  int w = t >> 6;
  if ((t & 63) == 0) { red[w] = s; red[4 + w] = ss; }
  __syncthreads();
  if (t == 0) {
    s = red[0] + red[1] + red[2] + red[3];
    ss = red[4] + red[5] + red[6] + red[7];
    float mean = s * (1.f / 65536.f);
    float var = ss * (1.f / 65536.f) - mean * mean;
    mv[0] = mean; mv[1] = rsqrtf(var + 1e-5f);
  }
  __syncthreads();
  float mean = mv[0], rstd = mv[1];
  const float* src = x + (size_t)bid * 65536;
  for (int ch = 0; ch < 16; ch++) {
#pragma unroll
    for (int i = 0; i < 4; i++) {
      int lin = t + i * 256;  // 0..1023
      int c = lin >> 4, p4 = lin & 15;
      float4 v = *(const float4*)(src + (size_t)c * 1024 + ch * 64 + p4 * 4);
      float gg = gw[g * 64 + c] * rstd;
      float bb = gb[g * 64 + c] - mean * gg;
      tile[c][p4 * 4 + 0] = v.x * gg + bb;
      tile[c][p4 * 4 + 1] = v.y * gg + bb;
      tile[c][p4 * 4 + 2] = v.z * gg + bb;
      tile[c][p4 * 4 + 3] = v.w * gg + bb;
    }
    __syncthreads();
    unsigned short* dst = xnT + ((size_t)b * 1024 + ch * 64) * 512 + g * 64;
#pragma unroll
    for (int i = 0; i < 4; i++) {
      int lin = t + i * 256;
      int pp = lin >> 4, cq = lin & 15;
      ushort4 o;
      o.x = f2bf(tile[cq * 4 + 0][pp]);
      o.y = f2bf(tile[cq * 4 + 1][pp]);
      o.z = f2bf(tile[cq * 4 + 2][pp]);
      o.w = f2bf(tile[cq * 4 + 3][pp]);
      *(ushort4*)(dst + (size_t)pp * 512 + cq * 4) = o;
    }
    __syncthreads();
  }
}

// ---------------- generic bf16 B^T GEMM: C[m,n] = sum_k A[m,k]*B[n,k] ----------------
// EPI: 0=none, 1=+bias[n], 2=+bias[m], 3=+bias[m]+res
template <int EPI, bool OUT_BF16>
__global__ __launch_bounds__(256) void gemm_bt(
    const unsigned short* __restrict__ A, int lda, long long sA,
    const unsigned short* __restrict__ B, int ldb, long long sB,
    void* __restrict__ Cv, int ldc, long long sC,
    const float* __restrict__ bias,
    const float* __restrict__ res, long long sRes,
    int M, int N, int K, int mt, int nt) {
  __shared__ __align__(16) unsigned short As[128 * 32];
  __shared__ __align__(16) unsigned short Bs[128 * 32];
  int bid = blockIdx.x;
  int per = mt * nt;
  int b = bid / per;
  int r = bid % per;
  int mi = r / nt, ni = r % nt;
  int t = threadIdx.x;
  int l = t & 63, w = t >> 6;
  int wm = w >> 1, wn = w & 1;
  int fr = l & 15;
  int fk = (l >> 4) << 3;
  const unsigned short* Ab = A + (size_t)b * sA + (size_t)(mi * 128) * lda;
  const unsigned short* Bb = B + (size_t)b * sB + (size_t)(ni * 128) * ldb;
  int sr = t >> 2, sk = (t & 3) << 3;
  const unsigned short* gA = Ab + (size_t)sr * lda + sk;
  const unsigned short* gB = Bb + (size_t)sr * ldb + sk;
  unsigned short* lA = As + w * 512;  // wave-uniform LDS dest
  unsigned short* lB = Bs + w * 512;
  const unsigned short* ra = As + (wm * 64 + fr) * 32 + fk;
  const unsigned short* rb = Bs + (wn * 64 + fr) * 32 + fk;
  f32x4 acc[4][4] = {};
  for (int k0 = 0; k0 < K; k0 += 32) {
    g2l16(gA, lA);
    g2l16(gA + (size_t)64 * lda, lA + 2048);
    g2l16(gB, lB);
    g2l16(gB + (size_t)64 * ldb, lB + 2048);
    gA += 32; gB += 32;
    __syncthreads();
    bf16x8 af[4], bv[4];
#pragma unroll
    for (int i = 0; i < 4; i++) af[i] = *(const bf16x8*)(ra + i * 512);
#pragma unroll
    for (int j = 0; j < 4; j++) bv[j] = *(const bf16x8*)(rb + j * 512);
#pragma unroll
    for (int i = 0; i < 4; i++)
#pragma unroll
      for (int j = 0; j < 4; j++)
        acc[i][j] = __builtin_amdgcn_mfma_f32_16x16x32_bf16(af[i], bv[j], acc[i][j], 0, 0, 0);
    __syncthreads();
  }
  int crow0 = mi * 128 + wm * 64;
  int ccol0 = ni * 128 + wn * 64;
  int lr = (l >> 4) << 2;
  int lc = l & 15;
#pragma unroll
  for (int i = 0; i < 4; i++) {
#pragma unroll
    for (int j = 0; j < 4; j++) {
      int col = ccol0 + j * 16 + lc;
      float bn = (EPI == 1) ? bias[col] : 0.0f;
#pragma unroll
      for (int e = 0; e < 4; e++) {
        int row = crow0 + i * 16 + lr + e;
        float v = acc[i][j][e];
        if (EPI == 1) v += bn;
        if (EPI == 2 || EPI == 3) v += bias[row];
        if (EPI == 3) v += res[(size_t)b * sRes + (size_t)row * ldc + col];
        size_t o = (size_t)b * sC + (size_t)row * ldc + col;
        if (OUT_BF16) ((unsigned short*)Cv)[o] = f2bf(v);
        else ((float*)Cv)[o] = v;
      }
    }
  }
}

// ---------------- flash attention v4: batch K/V register loads, raw barriers ----------------
// grid 256 (b, i-tile of 64 rows), 512 threads (8 waves).
// qkT[b][p][0..511]=Q, [512..1023]=K ; vbuf[b][c][p] ; obuf[b][p][c] bf16
// Wave w owns: S stripe cols w*16..w*16+15 (all 64 rows), PV d-slice w*64..w*64+63.
__global__ __launch_bounds__(512, 2) void flash_attn(
    const unsigned short* __restrict__ qkT, const unsigned short* __restrict__ vbuf,
    unsigned short* __restrict__ obuf) {
  // Q rows padded to 1040B -> b128 reads spread 8 lanes/bank-group (conflict-free).
  __shared__ __align__(16) unsigned short Qs[64 * 520];       // 66.6 KB
  __shared__ __align__(16) float Slds[64 * 132];              // 33.8 KB
  __shared__ __align__(16) unsigned short Plds[4 * 64 * 40];  // 20.5 KB: 4 kp-panels x [64r][80B]
  __shared__ float mrow[64], lrow[64], scl[64];

  const float SC = 0.04419417382415922f;  // 1/sqrt(512)
  int bid = blockIdx.x;
  int logical = (bid & 7) * 32 + (bid >> 3);  // 2 batches per XCD -> K+V L2-resident
  int b = logical >> 4, it = logical & 15;
  int i0 = it * 64;
  int tid = threadIdx.x;
  int l = tid & 63, w = tid >> 6;
  int fr = l & 15, fq = l >> 4;
  int d0 = w * 64;

  const size_t bq = (size_t)b * 1048576;
  const size_t bv = (size_t)b * 524288;

  // ---- stage Q once: call i stages rows i*8..i*8+7 (one row per wave) ----
  {
    const unsigned short* qsrc = qkT + bq + (size_t)i0 * 1024 + l * 8;
#pragma unroll
    for (int i = 0; i < 8; i++) {
      int row = i * 8 + w;
      g2l16(qsrc + (size_t)row * 1024, (char*)Qs + row * 1040);
    }
  }
  if (tid < 64) { mrow[tid] = -3e38f; lrow[tid] = 0.f; }
  __syncthreads();  // drains vmcnt -> Q ready

  f32x4 acc[4][4] = {};
  const unsigned short* kg = qkT + bq + 512 + (size_t)(w * 16 + fr) * 1024 + fq * 8;
  const unsigned short* vg = vbuf + bv + (size_t)(d0 + fr) * 1024 + fq * 8;

  // softmax lane remap: r = w*8 + (l&7), s8 = l>>3  -> consecutive lanes span 8 rows
  int smr = w * 8 + (l & 7);
  int sm8 = l >> 3;

#pragma unroll 1
  for (int jt = 0; jt < 8; jt++) {
    // ---- batch-issue K loads (consumed in S phase), then V loads (consumed in PV) ----
    const unsigned short* kgj = kg + (size_t)jt * 131072;  // 128 rows * 1024
    bf16x8 kf[16];
#pragma unroll
    for (int ks = 0; ks < 16; ks++) kf[ks] = *(const bf16x8*)(kgj + ks * 32);
    const unsigned short* vgj = vg + jt * 128;
    bf16x8 vf[16];
#pragma unroll
    for (int nj = 0; nj < 4; nj++)
#pragma unroll
      for (int kp = 0; kp < 4; kp++)
        vf[nj * 4 + kp] = *(const bf16x8*)(vgj + nj * 16384 + kp * 32);

    // ---- S phase: 4 m-frags x 1 n-frag(wave stripe), Q from LDS, K from regs ----
    {
      f32x4 sacc[4] = {};
#pragma unroll
      for (int ks = 0; ks < 16; ks++) {
#pragma unroll
        for (int mi = 0; mi < 4; mi++) {
          bf16x8 qa = *(const bf16x8*)((const char*)Qs + (mi * 16 + fr) * 1040 + (ks * 4 + fq) * 16);
          sacc[mi] = __builtin_amdgcn_mfma_f32_16x16x32_bf16(qa, kf[ks], sacc[mi], 0, 0, 0);
        }
      }
#pragma unroll
      for (int mi = 0; mi < 4; mi++) {
        float* sp = Slds + (mi * 16 + fq * 4) * 132 + w * 16 + fr;
#pragma unroll
        for (int e = 0; e < 4; e++) sp[e * 132] = sacc[mi][e];
      }
    }
    asm volatile("s_waitcnt lgkmcnt(0)" ::: "memory");
    __builtin_amdgcn_s_barrier();           // B1: S visible; vf still in flight
    __builtin_amdgcn_sched_barrier(0);

    // ---- online softmax: 8 threads/row x 16 cols each ----
    {
      int r = smr, s8 = sm8;
      const float* srowp = Slds + r * 132 + s8 * 16;
      float4 a0 = *(const float4*)(srowp + 0);
      float4 a1 = *(const float4*)(srowp + 4);
      float4 a2 = *(const float4*)(srowp + 8);
      float4 a3 = *(const float4*)(srowp + 12);
      float mx = fmaxf(fmaxf(fmaxf(a0.x, a0.y), fmaxf(a0.z, a0.w)),
                       fmaxf(fmaxf(a1.x, a1.y), fmaxf(a1.z, a1.w)));
      mx = fmaxf(mx, fmaxf(fmaxf(fmaxf(a2.x, a2.y), fmaxf(a2.z, a2.w)),
                           fmaxf(fmaxf(a3.x, a3.y), fmaxf(a3.z, a3.w))));
      mx = fmaxf(mx, __shfl_xor(mx, 8, 64));
      mx = fmaxf(mx, __shfl_xor(mx, 16, 64));
      mx = fmaxf(mx, __shfl_xor(mx, 32, 64));
      float mold = mrow[r];
      float mnew = fmaxf(mold, mx);
      float e0 = __expf((a0.x - mnew) * SC), e1 = __expf((a0.y - mnew) * SC);
      float e2 = __expf((a0.z - mnew) * SC), e3 = __expf((a0.w - mnew) * SC);
      float e4 = __expf((a1.x - mnew) * SC), e5 = __expf((a1.y - mnew) * SC);
      float e6 = __expf((a1.z - mnew) * SC), e7 = __expf((a1.w - mnew) * SC);
      float e8 = __expf((a2.x - mnew) * SC), e9 = __expf((a2.y - mnew) * SC);
      float ea = __expf((a2.z - mnew) * SC), eb = __expf((a2.w - mnew) * SC);
      float ec = __expf((a3.x - mnew) * SC), ed = __expf((a3.y - mnew) * SC);
      float ee = __expf((a3.z - mnew) * SC), ef = __expf((a3.w - mnew) * SC);
      float sum = ((e0 + e1) + (e2 + e3)) + ((e4 + e5) + (e6 + e7)) +
                  ((e8 + e9) + (ea + eb)) + ((ec + ed) + (ee + ef));
      sum += __shfl_xor(sum, 8, 64);
      sum += __shfl_xor(sum, 16, 64);
      sum += __shfl_xor(sum, 32, 64);
      uint4 pw0, pw1;
      pw0.x = f2bf(e0) | ((unsigned)f2bf(e1) << 16);
      pw0.y = f2bf(e2) | ((unsigned)f2bf(e3) << 16);
      pw0.z = f2bf(e4) | ((unsigned)f2bf(e5) << 16);
      pw0.w = f2bf(e6) | ((unsigned)f2bf(e7) << 16);
      pw1.x = f2bf(e8) | ((unsigned)f2bf(e9) << 16);
      pw1.y = f2bf(ea) | ((unsigned)f2bf(eb) << 16);
      pw1.z = f2bf(ec) | ((unsigned)f2bf(ed) << 16);
      pw1.w = f2bf(ee) | ((unsigned)f2bf(ef) << 16);
      char* pp = (char*)Plds + (s8 >> 1) * 5120 + r * 80 + (s8 & 1) * 32;
      *(uint4*)pp = pw0;
      *(uint4*)(pp + 16) = pw1;
      if (s8 == 0) {
        float sf = __expf((mold - mnew) * SC);
        lrow[r] = lrow[r] * sf + sum;
        mrow[r] = mnew;
        scl[r] = sf;
      }
    }
    asm volatile("s_waitcnt lgkmcnt(0)" ::: "memory");
    __builtin_amdgcn_s_barrier();           // B2: P + stats visible
    __builtin_amdgcn_sched_barrier(0);

    // ---- rescale acc, then PV: 4 m x 4 n x 4 kp, V from regs ----
    {
      f32x4 sc4[4];
#pragma unroll
      for (int mi = 0; mi < 4; mi++) sc4[mi] = *(const f32x4*)(scl + mi * 16 + fq * 4);
#pragma unroll
      for (int mi = 0; mi < 4; mi++)
#pragma unroll
        for (int nj = 0; nj < 4; nj++) acc[mi][nj] *= sc4[mi];
#pragma unroll
      for (int kp = 0; kp < 4; kp++) {
        bf16x8 pf[4];
#pragma unroll
        for (int mi = 0; mi < 4; mi++)
          pf[mi] = *(const bf16x8*)((const char*)Plds + kp * 5120 + (mi * 16 + fr) * 80 + fq * 16);
#pragma unroll
        for (int nj = 0; nj < 4; nj++) {
#pragma unroll
          for (int mi = 0; mi < 4; mi++)
            acc[mi][nj] = __builtin_amdgcn_mfma_f32_16x16x32_bf16(pf[mi], vf[nj * 4 + kp], acc[mi][nj], 0, 0, 0);
        }
      }
    }
  }

  // ---- epilogue: O /= l, store bf16 ----
  f32x4 linv[4];
#pragma unroll
  for (int mi = 0; mi < 4; mi++) {
    f32x4 lv = *(const f32x4*)(lrow + mi * 16 + fq * 4);
#pragma unroll
    for (int e = 0; e < 4; e++) linv[mi][e] = 1.0f / lv[e];
  }
  unsigned short* ob = obuf + bv + (size_t)i0 * 512 + d0 + fr;
#pragma unroll
  for (int mi = 0; mi < 4; mi++)
#pragma unroll
    for (int nj = 0; nj < 4; nj++)
#pragma unroll
      for (int e = 0; e < 4; e++) {
        int row = mi * 16 + fq * 4 + e;
        ob[(size_t)row * 512 + nj * 16] = f2bf(acc[mi][nj][e] * linv[mi][e]);
      }
}

extern "C" void kernel_launch(void* const* d_in, const int* in_sizes, int n_in,
                              void* d_out, int out_size, void* d_ws, size_t ws_size,
                              hipStream_t stream) {
  const float* x = (const float*)d_in[0];
  const float* norm_w = (const float*)d_in[1];
  const float* norm_b = (const float*)d_in[2];
  const float* qkv_w = (const float*)d_in[3];
  const float* qkv_b = (const float*)d_in[4];
  const float* proj_w = (const float*)d_in[5];
  const float* proj_b = (const float*)d_in[6];
  float* out = (float*)d_out;
  char* ws = (char*)d_ws;

  size_t off = 0;
  auto alloc = [&](size_t bytes) {
    off = (off + 255) & ~(size_t)255;
    size_t r = off; off += bytes; return r;
  };
  unsigned short* wqkv  = (unsigned short*)(ws + alloc((size_t)1536 * 512 * 2));
  unsigned short* wproj = (unsigned short*)(ws + alloc((size_t)512 * 512 * 2));
  unsigned short* xnT   = (unsigned short*)(ws + alloc((size_t)16 * 1024 * 512 * 2));
  unsigned short* qkT   = (unsigned short*)(ws + alloc((size_t)16 * 1024 * 1024 * 2));
  unsigned short* vbuf  = (unsigned short*)(ws + alloc((size_t)16 * 512 * 1024 * 2));
  unsigned short* obuf  = (unsigned short*)(ws + alloc((size_t)16 * 1024 * 512 * 2));

  cvt_weights<<<4096, 256, 0, stream>>>(qkv_w, proj_w, wqkv, wproj);
  gn_fused<<<128, 256, 0, stream>>>(x, norm_w, norm_b, xnT);

  // GEMM1: qkT[b][p][o] = sum_c xnT[b][p][c] * wqkv[o][c] + qkv_b[o], o in [0,1024)
  gemm_bt<1, true><<<1024, 256, 0, stream>>>(
      xnT, 512, 1024LL * 512, wqkv, 512, 0,
      qkT, 1024, 1024LL * 1024, qkv_b, nullptr, 0, 1024, 1024, 512, 8, 8);

  // GEMM2: v[b][c][p] = sum_cc wv[c][cc] * xnT[b][p][cc] + qkv_b[1024+c]
  gemm_bt<2, true><<<512, 256, 0, stream>>>(
      wqkv + (size_t)1024 * 512, 512, 0, xnT, 512, 1024LL * 512,
      vbuf, 1024, 512LL * 1024, qkv_b + 1024, nullptr, 0, 512, 1024, 512, 4, 8);

  // fused attention: obuf[b][p][c] = softmax(Q K^T / sqrt(512)) V
  flash_attn<<<256, 512, 0, stream>>>(qkT, vbuf, obuf);

  // GEMM5: out[b][o][p] = sum_c wproj[o][c] * obuf[b][p][c] + proj_b[o] + x[b][o][p]
  gemm_bt<3, false><<<512, 256, 0, stream>>>(
      wproj, 512, 0, obuf, 512, 1024LL * 512,
      out, 1024, 512LL * 1024, proj_b, x, 512LL * 1024, 512, 1024, 512, 4, 8);
}